// Round 7
// baseline (225.706 us; speedup 1.0000x reference)
//
#include <hip/hip_runtime.h>
#include <hip/hip_bf16.h>

#define IMG 1024
#define OUTW 1018
#define RS 36                  // output rows owned per strip (round-4 winner)
#define NSTRIP 29              // 29*36 = 1044 >= 1018
#define NXW 4                  // waves across width: 4*256 = 1024 cols
#define NBATCH 16
#define NBLK (NBATCH * NSTRIP * NXW)   // 1856 blocks, 1 wave each
#define NSTEP (RS + 8)                 // 44 row-steps per strip
#define EPSF 2.2204460492503131e-16f
#define INV81 (1.0f / 81.0f)

struct Row {
  float lI, lJ;
  float4 A1, B1, A2, B2, A3, B3;
};

__device__ __forceinline__ Row zero_row() {
  Row w;
  w.lI = w.lJ = 0.f;
  w.A1 = w.B1 = w.A2 = w.B2 = w.A3 = w.B3 = make_float4(0.f, 0.f, 0.f, 0.f);
  return w;
}

__device__ __forceinline__ Row load_row(const float* __restrict__ rpI,
                                        const float* __restrict__ rpJ,
                                        int ccL, int c0, int cc2, int cc3) {
  Row w;
  w.lI = rpI[ccL];
  w.lJ = rpJ[ccL];
  w.A1 = *(const float4*)(rpI + c0);
  w.B1 = *(const float4*)(rpJ + c0);
  w.A2 = *(const float4*)(rpI + cc2);
  w.B2 = *(const float4*)(rpJ + cc2);
  w.A3 = *(const float4*)(rpI + cc3);
  w.B3 = *(const float4*)(rpJ + cc3);
  return w;
}

// Horizontal 9-sums at 4 offsets from 12 positions; bf16 ring storage so the
// sliding-window subtract cancels exactly (value subtracted == value added 9
// rows earlier). Updates running vertical window wX[0..3] and ring row g[0..1].
__device__ __forceinline__ void hsum_update(const float* __restrict__ arr,
                                            float* __restrict__ wX,
                                            __hip_bfloat162* __restrict__ g) {
  float h0 = arr[0] + arr[1] + arr[2] + arr[3] + arr[4] + arr[5] + arr[6] +
             arr[7] + arr[8];
  float h1 = h0 - arr[0] + arr[9];
  float h2 = h1 - arr[1] + arr[10];
  float h3 = h2 - arr[2] + arr[11];
  __hip_bfloat162 plo = __float22bfloat162_rn(make_float2(h0, h1));
  __hip_bfloat162 phi = __float22bfloat162_rn(make_float2(h2, h3));
  float2 nlo = __bfloat1622float2(plo), nhi = __bfloat1622float2(phi);
  float2 olo = __bfloat1622float2(g[0]), ohi = __bfloat1622float2(g[1]);
  wX[0] += nlo.x - olo.x;
  wX[1] += nlo.y - olo.y;
  wX[2] += nhi.x - ohi.x;
  wX[3] += nhi.y - ohi.y;
  g[0] = plo;
  g[1] = phi;
}

__global__ __launch_bounds__(64, 1) void fused_kernel(
    const float* __restrict__ I, const float* __restrict__ J,
    double2* __restrict__ partial) {
  const int lane = threadIdx.x;
  const int wid = blockIdx.x;
  const int b = wid / (NSTRIP * NXW);
  const int rem = wid - b * (NSTRIP * NXW);
  const int strip = rem / NXW;
  const int xw = rem - strip * NXW;
  const int R0 = strip * RS;
  const int c0 = xw * 256 + 4 * lane;      // first owned column
  const int ccL = max(c0 - 1, 0);          // left-halo scalar col (clamped)
  const int cc2 = min(c0 + 4, IMG - 4);
  const int cc3 = min(c0 + 8, IMG - 4);
  const bool vL = (c0 > 0);
  const bool v2 = (c0 + 4 <= IMG - 4);
  const bool v3 = (c0 + 8 <= IMG - 4);
  const float* Ib = I + (size_t)b * (IMG * IMG);
  const float* Jb = J + (size_t)b * (IMG * IMG);

  // bf16-packed ring: 9 rows x 5 quantities x 4 cols = 90 VGPRs
  __hip_bfloat162 gI[9][2], gJ[9][2], gII[9][2], gJJ[9][2], gIJ[9][2];
  const __hip_bfloat162 z2 = __float22bfloat162_rn(make_float2(0.f, 0.f));
#pragma unroll
  for (int k = 0; k < 9; ++k) {
    gI[k][0] = z2; gI[k][1] = z2; gJ[k][0] = z2; gJ[k][1] = z2;
    gII[k][0] = z2; gII[k][1] = z2; gJJ[k][0] = z2; gJJ[k][1] = z2;
    gIJ[k][0] = z2; gIJ[k][1] = z2;
  }
  float wI[4] = {0,0,0,0}, wJ[4] = {0,0,0,0}, wII[4] = {0,0,0,0},
        wJJ[4] = {0,0,0,0}, wIJ[4] = {0,0,0,0};
  float prevI[4] = {0,0,0,0};
  float acc_cc = 0.f, acc_sm = 0.f;

  // process one already-loaded row; u (ring index) is compile-time constant
  auto process = [&](const Row& cur, int t, int u) {
    const int r = R0 - 1 + t;
    float iw[12], jw[12];
    iw[0] = vL ? cur.lI : 0.f;   jw[0] = vL ? cur.lJ : 0.f;
    iw[1] = cur.A1.x; iw[2] = cur.A1.y; iw[3] = cur.A1.z; iw[4] = cur.A1.w;
    jw[1] = cur.B1.x; jw[2] = cur.B1.y; jw[3] = cur.B1.z; jw[4] = cur.B1.w;
    iw[5] = v2 ? cur.A2.x : 0.f; iw[6] = v2 ? cur.A2.y : 0.f;
    iw[7] = v2 ? cur.A2.z : 0.f; iw[8] = v2 ? cur.A2.w : 0.f;
    jw[5] = v2 ? cur.B2.x : 0.f; jw[6] = v2 ? cur.B2.y : 0.f;
    jw[7] = v2 ? cur.B2.z : 0.f; jw[8] = v2 ? cur.B2.w : 0.f;
    iw[9]  = v3 ? cur.A3.x : 0.f; iw[10] = v3 ? cur.A3.y : 0.f;
    iw[11] = v3 ? cur.A3.z : 0.f;
    jw[9]  = v3 ? cur.B3.x : 0.f; jw[10] = v3 ? cur.B3.y : 0.f;
    jw[11] = v3 ? cur.B3.z : 0.f;

    hsum_update(iw, wI, gI[u]);
    hsum_update(jw, wJ, gJ[u]);
    {
      float pr[12];
#pragma unroll
      for (int p = 0; p < 12; ++p) pr[p] = iw[p] * iw[p];
      hsum_update(pr, wII, gII[u]);
#pragma unroll
      for (int p = 0; p < 12; ++p) pr[p] = jw[p] * jw[p];
      hsum_update(pr, wJJ, gJJ[u]);
#pragma unroll
      for (int p = 0; p < 12; ++p) pr[p] = iw[p] * jw[p];
      hsum_update(pr, wIJ, gIJ[u]);
    }

    // smoothness dy: pairs (r-1, r) with r-1 owned by this strip
    if (r >= R0 + 1 && r <= R0 + RS && r <= IMG - 1) {   // uniform
#pragma unroll
      for (int q = 0; q < 4; ++q) {
        float d = iw[1 + q] - prevI[q];
        acc_sm = fmaf(d, d, acc_sm);
      }
    }
    // smoothness dx at owned rows
    if (r >= R0 && r <= R0 + RS - 1 && r <= IMG - 1) {   // uniform
#pragma unroll
      for (int q = 0; q < 4; ++q) {
        float d = iw[2 + q] - iw[1 + q];
        d = (c0 + q < IMG - 1) ? d : 0.f;
        acc_sm = fmaf(d, d, acc_sm);
      }
    }
    prevI[0] = iw[1]; prevI[1] = iw[2]; prevI[2] = iw[3]; prevI[3] = iw[4];

    // emit output row oy = R0 + t - 8 once window complete
    if (t >= 8) {                                        // uniform
      const int oy = R0 + t - 8;
      if (oy < OUTW) {                                   // uniform
#pragma unroll
        for (int q = 0; q < 4; ++q) {
          if (c0 + q < OUTW) {
            float cross = fmaf(-(wI[q] * wJ[q]), INV81, wIJ[q]);
            float iva   = fmaf(-(wI[q] * wI[q]), INV81, wII[q]);
            float jva   = fmaf(-(wJ[q] * wJ[q]), INV81, wJJ[q]);
            float den   = fmaf(iva, jva, EPSF);
            acc_cc += cross * cross * __builtin_amdgcn_rcpf(den);
          }
        }
      }
    }
  };

  for (int tc = 0; tc < 5; ++tc) {
#pragma unroll
    for (int g = 0; g < 3; ++g) {
      // load 3 rows back-to-back, then process 3 — rows 2&3's latency hides
      // under row 1&2's compute. Ring index j = g*3+d stays compile-time.
      Row rw[3];
#pragma unroll
      for (int d = 0; d < 3; ++d) {
        const int t = tc * 9 + g * 3 + d;
        const int r = R0 - 1 + t;
        rw[d] = (t < NSTEP && r >= 0 && r < IMG)
                    ? load_row(Ib + ((size_t)r << 10), Jb + ((size_t)r << 10),
                               ccL, c0, cc2, cc3)
                    : zero_row();
      }
#pragma unroll
      for (int d = 0; d < 3; ++d) {
        const int j = g * 3 + d;     // ring index, compile-time
        const int t = tc * 9 + j;
        if (t < NSTEP) process(rw[d], t, j);
      }
    }
  }

  // wave reduce (block == 1 wave)
  float vc = acc_cc, vs = acc_sm;
#pragma unroll
  for (int off = 32; off > 0; off >>= 1) {
    vc += __shfl_down(vc, off);
    vs += __shfl_down(vs, off);
  }
  if (lane == 0) partial[wid] = make_double2((double)vc, (double)vs);
}

__global__ __launch_bounds__(256) void fin_kernel(const double2* __restrict__ partial,
                                                  float* __restrict__ out) {
  double s_cc = 0.0, s_sm = 0.0;
  for (int i = threadIdx.x; i < NBLK; i += 256) {
    double2 p = partial[i];
    s_cc += p.x; s_sm += p.y;
  }
#pragma unroll
  for (int off = 32; off > 0; off >>= 1) {
    s_cc += __shfl_down(s_cc, off);
    s_sm += __shfl_down(s_sm, off);
  }
  __shared__ double r1[4], r2[4];
  if ((threadIdx.x & 63) == 0) { r1[threadIdx.x >> 6] = s_cc; r2[threadIdx.x >> 6] = s_sm; }
  __syncthreads();
  if (threadIdx.x == 0) {
    const double cc = (r1[0] + r1[1] + r1[2] + r1[3]) /
                      (double)((size_t)NBATCH * OUTW * OUTW);
    const double sm = (r2[0] + r2[1] + r2[2] + r2[3]) /
                      (2.0 * (double)((size_t)NBATCH * IMG * (IMG - 1)));
    out[0] = (float)(-cc + 0.1 * sm);
  }
}

extern "C" void kernel_launch(void* const* d_in, const int* in_sizes, int n_in,
                              void* d_out, int out_size, void* d_ws, size_t ws_size,
                              hipStream_t stream) {
  const float* y  = (const float*)d_in[0];
  const float* yt = (const float*)d_in[1];
  float* out = (float*)d_out;
  double2* partial = (double2*)d_ws;
  fused_kernel<<<NBLK, 64, 0, stream>>>(y, yt, partial);
  fin_kernel<<<1, 256, 0, stream>>>(partial, out);
}

// Round 8
// 178.585 us; speedup vs baseline: 1.2639x; 1.2639x over previous
//
#include <hip/hip_runtime.h>
#include <hip/hip_bf16.h>

#define IMG 1024
#define OUTW 1018
#define RS 36                  // output rows owned per strip (round-4 winner)
#define NSTRIP 29              // 29*36 = 1044 >= 1018
#define NXW 4                  // waves across width: 4*256 = 1024 cols
#define NBATCH 16
#define NWAVE (NBATCH * NSTRIP * NXW)  // 1856 working waves
#define NBLK ((NWAVE + 3) / 4)         // 464 blocks of 4 waves
#define NSTEP (RS + 8)                 // 44 row-steps per strip
#define EPSF 2.2204460492503131e-16f
#define INV81 (1.0f / 81.0f)

// Linear horizontal 9-sum window update (bf16 ring for exact cancel).
__device__ __forceinline__ void hsum_update(const float* __restrict__ arr,
                                            float* __restrict__ wX,
                                            __hip_bfloat162* __restrict__ g) {
  float h0 = arr[0] + arr[1] + arr[2] + arr[3] + arr[4] + arr[5] + arr[6] +
             arr[7] + arr[8];
  float h1 = h0 - arr[0] + arr[9];
  float h2 = h1 - arr[1] + arr[10];
  float h3 = h2 - arr[2] + arr[11];
  __hip_bfloat162 plo = __float22bfloat162_rn(make_float2(h0, h1));
  __hip_bfloat162 phi = __float22bfloat162_rn(make_float2(h2, h3));
  float2 nlo = __bfloat1622float2(plo), nhi = __bfloat1622float2(phi);
  float2 olo = __bfloat1622float2(g[0]), ohi = __bfloat1622float2(g[1]);
  wX[0] += nlo.x - olo.x;
  wX[1] += nlo.y - olo.y;
  wX[2] += nhi.x - ohi.x;
  wX[3] += nhi.y - ohi.y;
  g[0] = plo;
  g[1] = phi;
}

// Quadratic (a[p]*b[p]) horizontal 9-sum window update, fmaf-fused.
__device__ __forceinline__ void hsum_update_sq(const float* __restrict__ a,
                                               const float* __restrict__ b,
                                               float* __restrict__ wX,
                                               __hip_bfloat162* __restrict__ g) {
  float h0 = a[0] * b[0];
  h0 = fmaf(a[1], b[1], h0); h0 = fmaf(a[2], b[2], h0);
  h0 = fmaf(a[3], b[3], h0); h0 = fmaf(a[4], b[4], h0);
  h0 = fmaf(a[5], b[5], h0); h0 = fmaf(a[6], b[6], h0);
  h0 = fmaf(a[7], b[7], h0); h0 = fmaf(a[8], b[8], h0);
  float h1 = fmaf(a[9],  b[9],  fmaf(-a[0], b[0], h0));
  float h2 = fmaf(a[10], b[10], fmaf(-a[1], b[1], h1));
  float h3 = fmaf(a[11], b[11], fmaf(-a[2], b[2], h2));
  __hip_bfloat162 plo = __float22bfloat162_rn(make_float2(h0, h1));
  __hip_bfloat162 phi = __float22bfloat162_rn(make_float2(h2, h3));
  float2 nlo = __bfloat1622float2(plo), nhi = __bfloat1622float2(phi);
  float2 olo = __bfloat1622float2(g[0]), ohi = __bfloat1622float2(g[1]);
  wX[0] += nlo.x - olo.x;
  wX[1] += nlo.y - olo.y;
  wX[2] += nhi.x - ohi.x;
  wX[3] += nhi.y - ohi.y;
  g[0] = plo;
  g[1] = phi;
}

__global__ __launch_bounds__(256, 1) void fused_kernel(
    const float* __restrict__ I, const float* __restrict__ J,
    double2* __restrict__ partial) {
  const int lane = threadIdx.x & 63;
  const int wid = blockIdx.x * 4 + (threadIdx.x >> 6);
  float acc_cc = 0.f, acc_sm = 0.f;
  {
    const int b = wid / (NSTRIP * NXW);
    const int rem = wid - b * (NSTRIP * NXW);
    const int strip = rem / NXW;
    const int xw = rem - strip * NXW;
    const int R0 = strip * RS;
    const int c0 = xw * 256 + 4 * lane;      // first owned column
    const int ccL = max(c0 - 1, 0);          // left-halo scalar col (clamped)
    const int cc2 = min(c0 + 4, IMG - 4);
    const int cc3 = min(c0 + 8, IMG - 4);
    const bool vL = (c0 > 0);
    const bool v2 = (c0 + 4 <= IMG - 4);
    const bool v3 = (c0 + 8 <= IMG - 4);
    const float* Ib = I + (size_t)b * (IMG * IMG);
    const float* Jb = J + (size_t)b * (IMG * IMG);

    // bf16-packed ring: 9 rows x 5 quantities x 4 cols = 90 VGPRs
    __hip_bfloat162 gI[9][2], gJ[9][2], gII[9][2], gJJ[9][2], gIJ[9][2];
    const __hip_bfloat162 z2 = __float22bfloat162_rn(make_float2(0.f, 0.f));
#pragma unroll
    for (int k = 0; k < 9; ++k) {
      gI[k][0] = z2; gI[k][1] = z2; gJ[k][0] = z2; gJ[k][1] = z2;
      gII[k][0] = z2; gII[k][1] = z2; gJJ[k][0] = z2; gJJ[k][1] = z2;
      gIJ[k][0] = z2; gIJ[k][1] = z2;
    }
    float wI[4] = {0,0,0,0}, wJ[4] = {0,0,0,0}, wII[4] = {0,0,0,0},
          wJJ[4] = {0,0,0,0}, wIJ[4] = {0,0,0,0};
    float prevI[4] = {0,0,0,0};

    for (int tc = 0; tc < 5; ++tc) {
#pragma unroll
      for (int u = 0; u < 9; ++u) {
        const int t = tc * 9 + u;
        if (t < NSTEP) {
          const int r = R0 - 1 + t;      // input row
          float iw[12], jw[12];
          if (r >= 0 && r < IMG) {       // wave-uniform
            const float* rpI = Ib + ((size_t)r << 10);
            const float* rpJ = Jb + ((size_t)r << 10);
            float lI = rpI[ccL], lJ = rpJ[ccL];
            float4 A1 = *(const float4*)(rpI + c0);
            float4 B1 = *(const float4*)(rpJ + c0);
            float4 A2 = *(const float4*)(rpI + cc2);
            float4 B2 = *(const float4*)(rpJ + cc2);
            float4 A3 = *(const float4*)(rpI + cc3);
            float4 B3 = *(const float4*)(rpJ + cc3);
            iw[0] = vL ? lI : 0.f;             jw[0] = vL ? lJ : 0.f;
            iw[1] = A1.x; iw[2] = A1.y; iw[3] = A1.z; iw[4] = A1.w;
            jw[1] = B1.x; jw[2] = B1.y; jw[3] = B1.z; jw[4] = B1.w;
            iw[5] = v2 ? A2.x : 0.f; iw[6] = v2 ? A2.y : 0.f;
            iw[7] = v2 ? A2.z : 0.f; iw[8] = v2 ? A2.w : 0.f;
            jw[5] = v2 ? B2.x : 0.f; jw[6] = v2 ? B2.y : 0.f;
            jw[7] = v2 ? B2.z : 0.f; jw[8] = v2 ? B2.w : 0.f;
            iw[9] = v3 ? A3.x : 0.f; iw[10] = v3 ? A3.y : 0.f; iw[11] = v3 ? A3.z : 0.f;
            jw[9] = v3 ? B3.x : 0.f; jw[10] = v3 ? B3.y : 0.f; jw[11] = v3 ? B3.z : 0.f;
          } else {
#pragma unroll
            for (int p = 0; p < 12; ++p) { iw[p] = 0.f; jw[p] = 0.f; }
          }

          hsum_update(iw, wI, gI[u]);
          hsum_update(jw, wJ, gJ[u]);
          hsum_update_sq(iw, iw, wII, gII[u]);
          hsum_update_sq(jw, jw, wJJ, gJJ[u]);
          hsum_update_sq(iw, jw, wIJ, gIJ[u]);

          // smoothness dy: pairs (r-1, r) with r-1 owned by this strip
          if (r >= R0 + 1 && r <= R0 + RS && r <= IMG - 1) {   // uniform
#pragma unroll
            for (int q = 0; q < 4; ++q) {
              float d = iw[1 + q] - prevI[q];
              acc_sm = fmaf(d, d, acc_sm);
            }
          }
          // smoothness dx at owned rows
          if (r >= R0 && r <= R0 + RS - 1 && r <= IMG - 1) {   // uniform
#pragma unroll
            for (int q = 0; q < 4; ++q) {
              float d = iw[2 + q] - iw[1 + q];
              d = (c0 + q < IMG - 1) ? d : 0.f;
              acc_sm = fmaf(d, d, acc_sm);
            }
          }
          prevI[0] = iw[1]; prevI[1] = iw[2]; prevI[2] = iw[3]; prevI[3] = iw[4];

          // emit output row oy = R0 + t - 8 once window complete
          if (t >= 8) {                                        // uniform
            const int oy = R0 + t - 8;
            if (oy < OUTW) {                                   // uniform
#pragma unroll
              for (int q = 0; q < 4; ++q) {
                if (c0 + q < OUTW) {
                  float cross = fmaf(-(wI[q] * wJ[q]), INV81, wIJ[q]);
                  float iva   = fmaf(-(wI[q] * wI[q]), INV81, wII[q]);
                  float jva   = fmaf(-(wJ[q] * wJ[q]), INV81, wJJ[q]);
                  float den   = fmaf(iva, jva, EPSF);
                  acc_cc += cross * cross * __builtin_amdgcn_rcpf(den);
                }
              }
            }
          }
        }
      }
    }
  }

  // per-wave reduce; one double2 per wave
  float vc = acc_cc, vs = acc_sm;
#pragma unroll
  for (int off = 32; off > 0; off >>= 1) {
    vc += __shfl_down(vc, off);
    vs += __shfl_down(vs, off);
  }
  if (lane == 0) partial[wid] = make_double2((double)vc, (double)vs);
}

__global__ __launch_bounds__(256) void fin_kernel(const double2* __restrict__ partial,
                                                  float* __restrict__ out) {
  double s_cc = 0.0, s_sm = 0.0;
  for (int i = threadIdx.x; i < NWAVE; i += 256) {
    double2 p = partial[i];
    s_cc += p.x; s_sm += p.y;
  }
#pragma unroll
  for (int off = 32; off > 0; off >>= 1) {
    s_cc += __shfl_down(s_cc, off);
    s_sm += __shfl_down(s_sm, off);
  }
  __shared__ double r1[4], r2[4];
  if ((threadIdx.x & 63) == 0) { r1[threadIdx.x >> 6] = s_cc; r2[threadIdx.x >> 6] = s_sm; }
  __syncthreads();
  if (threadIdx.x == 0) {
    const double cc = (r1[0] + r1[1] + r1[2] + r1[3]) /
                      (double)((size_t)NBATCH * OUTW * OUTW);
    const double sm = (r2[0] + r2[1] + r2[2] + r2[3]) /
                      (2.0 * (double)((size_t)NBATCH * IMG * (IMG - 1)));
    out[0] = (float)(-cc + 0.1 * sm);
  }
}

extern "C" void kernel_launch(void* const* d_in, const int* in_sizes, int n_in,
                              void* d_out, int out_size, void* d_ws, size_t ws_size,
                              hipStream_t stream) {
  const float* y  = (const float*)d_in[0];
  const float* yt = (const float*)d_in[1];
  float* out = (float*)d_out;
  double2* partial = (double2*)d_ws;
  fused_kernel<<<NBLK, 256, 0, stream>>>(y, yt, partial);
  fin_kernel<<<1, 256, 0, stream>>>(partial, out);
}